// Round 1
// baseline (357.720 us; speedup 1.0000x reference)
//
#include <hip/hip_runtime.h>

#define NB 1024
#define NT 256
#define IND 10
#define HID 64

#define KSTEPS 14              // K = 448 (14 x 32)
#define XS 456                 // X row stride in halves (456/8=57 odd -> conflict-free b128)
#define WMF_HALVES (KSTEPS * 4 * 64 * 8)   // 28672 halves = 57344 B

typedef short bf16x8 __attribute__((ext_vector_type(8)));
typedef float f32x4 __attribute__((ext_vector_type(4)));

__device__ __forceinline__ int qmap(int kk) {
    if (kk < 10) return 1 + kk;
    if (kk < 20) return 11 * (kk - 10 + 1);
    int i = (kk - 20) / 10, c = (kk - 20) % 10;
    return 11 * (i + 1) + 1 + c;
}

__device__ __forceinline__ unsigned bf16rne(float x) {
    unsigned u = __float_as_uint(x);
    return (u + 0x7fffu + ((u >> 16) & 1u)) >> 16;
}
__device__ __forceinline__ unsigned pk2(float a, float b) {
    return bf16rne(a) | (bf16rne(b) << 16);
}

// X column semantics (K=448):
//  [0,128):   P (wave slice w at 32w+i, i<30; scaled by inv_k for comps<20)
//  [128,256): rel0 * P
//  [256,384): rel1 * P
//  [384,400): rel2 * Pd (Pd = P[0..9], P[10], P[20..24])
//  [400,410): rel ; [410,420): F ; [420,424): ttv, ttv*rel0, ttv*rel1, ttv*rel2
//  [424]: gate ; [425]: 1.0 (bias) ; rest 0
__device__ float wm_value(int kk, int j, const float* __restrict__ W1,
                          const float* __restrict__ b1) {
    if (kk < 384) {
        int sec = kk >> 7;
        int rem = kk & 127;
        int w = rem >> 5, i = rem & 31;
        if (i >= 30) return 0.f;
        int q = qmap(30 * w + i);
        if (sec == 0) return W1[(11 + q) * 64 + j] + W1[(132 + q) * 64 + j];
        if (sec == 1) return W1[(253 + q) * 64 + j];
        return W1[(374 + q) * 64 + j];
    }
    if (kk < 400) {
        int i = kk - 384;
        if (i < 10) return W1[(496 + i) * 64 + j];
        if (i == 10) return W1[506 * 64 + j];
        return W1[(507 + (i - 11)) * 64 + j];
    }
    if (kk < 410) return W1[(1 + (kk - 400)) * 64 + j];
    if (kk < 420) return W1[(512 + (kk - 410)) * 64 + j];
    if (kk == 420) return W1[11 * 64 + j] + W1[132 * 64 + j];
    if (kk == 421) return W1[253 * 64 + j];
    if (kk == 422) return W1[374 * 64 + j];
    if (kk == 423) return W1[495 * 64 + j];
    if (kk == 424) return W1[0 * 64 + j];
    if (kk == 425) return b1[j];
    return 0.f;
}

// Wmf in exact B-fragment order: record (s, jb) is 64 lanes x 8 halves:
// lane (n = lane&15, quad = lane>>4) holds Wm[32s + quad*8 + idx][16jb + n].
__global__ void pack_mfma_kernel(const float* __restrict__ W1,
                                 const float* __restrict__ b1,
                                 unsigned short* __restrict__ Wmf) {
    int idx = blockIdx.x * 256 + threadIdx.x;
    if (idx >= WMF_HALVES) return;
    int half = idx & 7;
    int lane = (idx >> 3) & 63;
    int rec = idx >> 9;           // s*4 + jb
    int s = rec >> 2, jb = rec & 3;
    int kk = 32 * s + (lane >> 4) * 8 + half;
    int j = 16 * jb + (lane & 15);
    Wmf[idx] = (unsigned short)bf16rne(wm_value(kk, j, W1, b1));
}

// ---------------------------------------------------------------------------
// presig v9 (unchanged this round): scan phase spill-free; j-phase MFMA GEMM
// pre[64t][64j] = X[64t][448] . Wm[448][64j] in bf16.
// ---------------------------------------------------------------------------
__global__ __launch_bounds__(256, 1) void presig9_kernel(
    const float* __restrict__ features, const unsigned short* __restrict__ Wmf,
    float* __restrict__ pre1) {
    const int b = blockIdx.x;
    const int tid = threadIdx.x;
    const int l = tid & 63;
    const int wu = tid >> 6;

    __shared__ __align__(16) float sF[NT * IND];            // 10240 B
    __shared__ __align__(16) unsigned short sX[64 * XS];    // 58368 B
    __shared__ float sBase[128];                            // 512 B

    {
        const float4* src = (const float4*)(features + b * (NT * IND));
        float4* dst = (float4*)sF;
        for (int e = tid; e < NT * IND / 4; e += 256) dst[e] = src[e];
    }
    float f0[IND];
#pragma unroll
    for (int c = 0; c < IND; ++c) f0[c] = features[b * (NT * IND) + c];

    if (tid < 128) sBase[tid] = 0.f;
    __syncthreads();   // B0: sF + sBase ready

    for (int tile = 0; tile < 4; ++tile) {
        const int t0 = tile * 64;

        // ---- scan phase (identical math to presig7, proven) ----
        const int r = t0 + l;
        float rf = (float)r;
        float fr[IND], rel[IND], inc[IND];
#pragma unroll
        for (int c = 0; c < IND; ++c) fr[c] = sF[r * IND + c];
#pragma unroll
        for (int c = 0; c < IND; ++c) rel[c] = fr[c] - f0[c];
        {
            bool last = (r >= NT - 1);
#pragma unroll
            for (int c = 0; c < IND; ++c)
                inc[c] = last ? 0.f : (sF[(r + 1) * IND + c] - fr[c]);
        }
        float p[30], own[30];
        if (wu == 0) {
#pragma unroll
            for (int c = 0; c < 10; ++c) p[c] = rf * inc[c];
#pragma unroll
            for (int i = 0; i < 10; ++i) p[10 + i] = rel[i];
#pragma unroll
            for (int c = 0; c < 10; ++c) p[20 + c] = rel[0] * inc[c];
        } else {
            const int i0 = 3 * wu - 2;
#pragma unroll
            for (int q = 0; q < 30; ++q) {
                int i = i0 + q / 10, c = q % 10;
                p[q] = rel[i] * inc[c];
            }
        }
#pragma unroll
        for (int i = 0; i < 30; ++i) own[i] = p[i];
#pragma unroll
        for (int dsh = 0; dsh < 6; ++dsh) {
            const int d = 1 << dsh;
            bool ok = (l >= d);
#pragma unroll
            for (int i = 0; i < 30; ++i) {
                float v = __shfl_up(p[i], d, 64);
                if (ok) p[i] += v;
            }
        }
        float inv_r = (r > 0) ? 1.f / rf : 0.f;
        float v[30];
#pragma unroll
        for (int i = 0; i < 30; ++i) {
            float x = sBase[wu * 32 + i] + p[i] - own[i];
            if (wu == 0 && i < 20) x *= inv_r;
            v[i] = x;
        }

        // ---- build X (bf16), immediate uint4 stores (no big live arrays) ----
        {
            float g0 = rel[0], g1 = rel[1];
            uint4* xr = (uint4*)&sX[l * XS];           // raw P at halves 32*wu
            uint4* x0 = (uint4*)&sX[l * XS + 128];     // rel0*P
            uint4* x1 = (uint4*)&sX[l * XS + 256];     // rel1*P
            int qb = 8 * wu;
#pragma unroll
            for (int q = 0; q < 3; ++q) {
                uint4 tr, t0v, t1v;
                tr.x = pk2(v[8*q+0], v[8*q+1]); tr.y = pk2(v[8*q+2], v[8*q+3]);
                tr.z = pk2(v[8*q+4], v[8*q+5]); tr.w = pk2(v[8*q+6], v[8*q+7]);
                t0v.x = pk2(g0*v[8*q+0], g0*v[8*q+1]); t0v.y = pk2(g0*v[8*q+2], g0*v[8*q+3]);
                t0v.z = pk2(g0*v[8*q+4], g0*v[8*q+5]); t0v.w = pk2(g0*v[8*q+6], g0*v[8*q+7]);
                t1v.x = pk2(g1*v[8*q+0], g1*v[8*q+1]); t1v.y = pk2(g1*v[8*q+2], g1*v[8*q+3]);
                t1v.z = pk2(g1*v[8*q+4], g1*v[8*q+5]); t1v.w = pk2(g1*v[8*q+6], g1*v[8*q+7]);
                xr[wu * 4 + q] = tr; x0[wu * 4 + q] = t0v; x1[wu * 4 + q] = t1v;
            }
            {   // tail: v[24..29] + 2 zero halves
                uint4 tr, t0v, t1v;
                tr.x = pk2(v[24], v[25]); tr.y = pk2(v[26], v[27]);
                tr.z = pk2(v[28], v[29]); tr.w = 0u;
                t0v.x = pk2(g0*v[24], g0*v[25]); t0v.y = pk2(g0*v[26], g0*v[27]);
                t0v.z = pk2(g0*v[28], g0*v[29]); t0v.w = 0u;
                t1v.x = pk2(g1*v[24], g1*v[25]); t1v.y = pk2(g1*v[26], g1*v[27]);
                t1v.z = pk2(g1*v[28], g1*v[29]); t1v.w = 0u;
                xr[wu * 4 + 3] = tr; x0[wu * 4 + 3] = t0v; x1[wu * 4 + 3] = t1v;
            }
            (void)qb;
        }
        if (wu == 0) {   // extras: halves [384,456) of row l
            float g2 = rel[2];
            float ttv = 0.5f * (rf - 1.f) * inv_r;
            float gate = (r > 0) ? 1.f : 0.f;
            uint4* xe = (uint4*)&sX[l * XS + 384];
            uint4 u;
            u.x = pk2(g2*v[0], g2*v[1]);  u.y = pk2(g2*v[2], g2*v[3]);
            u.z = pk2(g2*v[4], g2*v[5]);  u.w = pk2(g2*v[6], g2*v[7]);
            xe[0] = u;
            u.x = pk2(g2*v[8], g2*v[9]);  u.y = pk2(g2*v[10], g2*v[20]);
            u.z = pk2(g2*v[21], g2*v[22]); u.w = pk2(g2*v[23], g2*v[24]);
            xe[1] = u;
            u.x = pk2(rel[0], rel[1]); u.y = pk2(rel[2], rel[3]);
            u.z = pk2(rel[4], rel[5]); u.w = pk2(rel[6], rel[7]);
            xe[2] = u;
            u.x = pk2(rel[8], rel[9]); u.y = pk2(fr[0], fr[1]);
            u.z = pk2(fr[2], fr[3]);   u.w = pk2(fr[4], fr[5]);
            xe[3] = u;
            u.x = pk2(fr[6], fr[7]); u.y = pk2(fr[8], fr[9]);
            u.z = pk2(ttv, ttv * rel[0]); u.w = pk2(ttv * rel[1], ttv * rel[2]);
            xe[4] = u;
            u.x = pk2(gate, 1.0f); u.y = 0u; u.z = 0u; u.w = 0u;
            xe[5] = u;
            u.x = 0u; u.y = 0u; u.z = 0u; u.w = 0u;
            xe[6] = u; xe[7] = u;
        }
        if (l == 63) {
#pragma unroll
            for (int i = 0; i < 30; ++i) sBase[wu * 32 + i] += p[i];
        }
        __syncthreads();   // Bx: X complete (cross-wave reads next)

        // ---- MFMA j-phase: wave wu computes t-rows [16wu,16wu+16) x all j ----
        {
            const int m = l & 15, quad = l >> 4;
            const unsigned short* arow = &sX[(16 * wu + m) * XS + 8 * quad];
            const bf16x8* bp = (const bf16x8*)Wmf;
            f32x4 ac0 = {0.f, 0.f, 0.f, 0.f}, ac1 = ac0, ac2 = ac0, ac3 = ac0;
#pragma unroll
            for (int s = 0; s < KSTEPS; ++s) {
                bf16x8 af = *(const bf16x8*)(arow + 32 * s);
                bf16x8 bf0 = bp[(s * 4 + 0) * 64 + l];
                bf16x8 bf1 = bp[(s * 4 + 1) * 64 + l];
                bf16x8 bf2 = bp[(s * 4 + 2) * 64 + l];
                bf16x8 bf3 = bp[(s * 4 + 3) * 64 + l];
                ac0 = __builtin_amdgcn_mfma_f32_16x16x32_bf16(af, bf0, ac0, 0, 0, 0);
                ac1 = __builtin_amdgcn_mfma_f32_16x16x32_bf16(af, bf1, ac1, 0, 0, 0);
                ac2 = __builtin_amdgcn_mfma_f32_16x16x32_bf16(af, bf2, ac2, 0, 0, 0);
                ac3 = __builtin_amdgcn_mfma_f32_16x16x32_bf16(af, bf3, ac3, 0, 0, 0);
            }
            float* op = pre1 + b * (NT * HID) + (t0 + 16 * wu) * HID + m;
            const int rowb = quad * 4;
#pragma unroll
            for (int reg = 0; reg < 4; ++reg) {
                op[(rowb + reg) * HID + 0]  = ac0[reg];
                op[(rowb + reg) * HID + 16] = ac1[reg];
                op[(rowb + reg) * HID + 32] = ac2[reg];
                op[(rowb + reg) * HID + 48] = ac3[reg];
            }
        }
        __syncthreads();   // Be: all X reads done before next tile rewrites
    }
}

// ---------------------------------------------------------------------------
// scan v2: TWO interleaved recurrences per wave (batches 2b, 2b+1), 512
// blocks.  Rationale: scan is latency-bound at 1 wave/SIMD (per-step 1080 cy
// vs ~180 cy issue work); the sibling batch's GEMV/DPP fills the LDS-latency
// and reduce-latency stalls.  W2 regs are SHARED between the two batches and
// pinned in VGPRs via empty asm (+v) so the allocator cannot rematerialize
// them per step (old kernel reported VGPR_Count=64 -- too small to hold the
// 64 loop-invariant W2 floats, i.e. they were being refetched every step).
// ---------------------------------------------------------------------------
template <int CTRL, int RMASK>
__device__ __forceinline__ float dpp_add(float x) {
    int v = __builtin_amdgcn_update_dpp(0, __float_as_int(x), CTRL, RMASK, 0xf, false);
    return x + __int_as_float(v);
}

#define W2_EACH(X) X(0) X(1) X(2) X(3) X(4) X(5) X(6) X(7) \
    X(8) X(9) X(10) X(11) X(12) X(13) X(14) X(15)

__global__ __launch_bounds__(64, 1) void scan2_kernel(
    const float* __restrict__ pre1, const float* __restrict__ W1,
    const float* __restrict__ W2, const float* __restrict__ b2,
    const float* __restrict__ W3, const float* __restrict__ b3,
    float* __restrict__ out) {
    const int bA = blockIdx.x * 2;
    const int bB = bA + 1;
    const int j = threadIdx.x;

    __shared__ __align__(16) float sHA[64];
    __shared__ __align__(16) float sHB[64];

#define DECLW(q) float4 w2_##q = make_float4( \
        W2[(4*(q)+0)*64 + j], W2[(4*(q)+1)*64 + j], \
        W2[(4*(q)+2)*64 + j], W2[(4*(q)+3)*64 + j]);
    W2_EACH(DECLW)
#undef DECLW
    // Pin loop-invariant W2 values in VGPRs (defeat rematerialization).
#define PINW(q) asm volatile("" : "+v"(w2_##q.x), "+v"(w2_##q.y), \
                                   "+v"(w2_##q.z), "+v"(w2_##q.w));
    W2_EACH(PINW)
#undef PINW
    float w1l = W1[522 * 64 + j];
    float b2j = b2[j], w3j = W3[j], b3v = b3[0];

    const float* pA_ = pre1 + bA * (NT * HID);
    const float* pB_ = pre1 + bB * (NT * HID);
    float deltaA = 0.f, deltaB = 0.f;
    float outbufA = 0.f, outbufB = 0.f;

#define GEMVQ2(q) { \
        float4 hA = *(const float4*)&sHA[4*(q)]; \
        float4 hB = *(const float4*)&sHB[4*(q)]; \
        a0A = fmaf(hA.x, w2_##q.x, a0A); a0B = fmaf(hB.x, w2_##q.x, a0B); \
        a1A = fmaf(hA.y, w2_##q.y, a1A); a1B = fmaf(hB.y, w2_##q.y, a1B); \
        a2A = fmaf(hA.z, w2_##q.z, a2A); a2B = fmaf(hB.z, w2_##q.z, a2B); \
        a3A = fmaf(hA.w, w2_##q.w, a3A); a3B = fmaf(hB.w, w2_##q.w, a3B); }

#define SCAN_STEP2(pvA, pvB, mm) { \
        float h1A = fmaxf(fmaf(deltaA, w1l, (pvA)), 0.f); \
        float h1B = fmaxf(fmaf(deltaB, w1l, (pvB)), 0.f); \
        sHA[j] = h1A; sHB[j] = h1B; \
        float a0A = 0.f, a1A = 0.f, a2A = 0.f, a3A = 0.f; \
        float a0B = 0.f, a1B = 0.f, a2B = 0.f, a3B = 0.f; \
        W2_EACH(GEMVQ2) \
        float h2A = fmaxf((a0A + a1A) + (a2A + a3A) + b2j, 0.f); \
        float h2B = fmaxf((a0B + a1B) + (a2B + a3B) + b2j, 0.f); \
        float qvA = h2A * w3j; \
        float qvB = h2B * w3j; \
        qvA = dpp_add<0x111, 0xf>(qvA); qvB = dpp_add<0x111, 0xf>(qvB); \
        qvA = dpp_add<0x112, 0xf>(qvA); qvB = dpp_add<0x112, 0xf>(qvB); \
        qvA = dpp_add<0x114, 0xf>(qvA); qvB = dpp_add<0x114, 0xf>(qvB); \
        qvA = dpp_add<0x118, 0xf>(qvA); qvB = dpp_add<0x118, 0xf>(qvB); \
        qvA = dpp_add<0x142, 0xa>(qvA); qvB = dpp_add<0x142, 0xa>(qvB); \
        qvA = dpp_add<0x143, 0xc>(qvA); qvB = dpp_add<0x143, 0xc>(qvB); \
        float totA = __uint_as_float(__builtin_amdgcn_readlane(__float_as_uint(qvA), 63)); \
        float totB = __uint_as_float(__builtin_amdgcn_readlane(__float_as_uint(qvB), 63)); \
        deltaA = totA + b3v; deltaB = totB + b3v; \
        if (j == ((mm) & 63)) { outbufA = deltaA; outbufB = deltaB; } \
        if (((mm) & 63) == 63) { \
            out[bA * NT + ((mm) & ~63) + j] = outbufA; \
            out[bB * NT + ((mm) & ~63) + j] = outbufB; } }

    float rA0 = pA_[0 * 64 + j], rA1 = pA_[1 * 64 + j], rA2 = pA_[2 * 64 + j],
          rA3 = pA_[3 * 64 + j], rA4 = pA_[4 * 64 + j], rA5 = pA_[5 * 64 + j],
          rA6 = pA_[6 * 64 + j], rA7 = pA_[7 * 64 + j];
    float rB0 = pB_[0 * 64 + j], rB1 = pB_[1 * 64 + j], rB2 = pB_[2 * 64 + j],
          rB3 = pB_[3 * 64 + j], rB4 = pB_[4 * 64 + j], rB5 = pB_[5 * 64 + j],
          rB6 = pB_[6 * 64 + j], rB7 = pB_[7 * 64 + j];
    for (int g = 0; g < NT; g += 8) {
        int nb = g + 8;
        float nA0 = pA_[min(nb + 0, NT - 1) * 64 + j];
        float nB0 = pB_[min(nb + 0, NT - 1) * 64 + j];
        float nA1 = pA_[min(nb + 1, NT - 1) * 64 + j];
        float nB1 = pB_[min(nb + 1, NT - 1) * 64 + j];
        float nA2 = pA_[min(nb + 2, NT - 1) * 64 + j];
        float nB2 = pB_[min(nb + 2, NT - 1) * 64 + j];
        float nA3 = pA_[min(nb + 3, NT - 1) * 64 + j];
        float nB3 = pB_[min(nb + 3, NT - 1) * 64 + j];
        float nA4 = pA_[min(nb + 4, NT - 1) * 64 + j];
        float nB4 = pB_[min(nb + 4, NT - 1) * 64 + j];
        float nA5 = pA_[min(nb + 5, NT - 1) * 64 + j];
        float nB5 = pB_[min(nb + 5, NT - 1) * 64 + j];
        float nA6 = pA_[min(nb + 6, NT - 1) * 64 + j];
        float nB6 = pB_[min(nb + 6, NT - 1) * 64 + j];
        float nA7 = pA_[min(nb + 7, NT - 1) * 64 + j];
        float nB7 = pB_[min(nb + 7, NT - 1) * 64 + j];
        SCAN_STEP2(rA0, rB0, g + 0)
        SCAN_STEP2(rA1, rB1, g + 1)
        SCAN_STEP2(rA2, rB2, g + 2)
        SCAN_STEP2(rA3, rB3, g + 3)
        SCAN_STEP2(rA4, rB4, g + 4)
        SCAN_STEP2(rA5, rB5, g + 5)
        SCAN_STEP2(rA6, rB6, g + 6)
        SCAN_STEP2(rA7, rB7, g + 7)
        rA0 = nA0; rA1 = nA1; rA2 = nA2; rA3 = nA3;
        rA4 = nA4; rA5 = nA5; rA6 = nA6; rA7 = nA7;
        rB0 = nB0; rB1 = nB1; rB2 = nB2; rB3 = nB3;
        rB4 = nB4; rB5 = nB5; rB6 = nB6; rB7 = nB7;
    }
#undef SCAN_STEP2
#undef GEMVQ2
}

// ---------------------------------------------------------------------------
// Fallback (round-1 fused kernel) if workspace is too small.
// ---------------------------------------------------------------------------
__global__ __launch_bounds__(256) void logsig_hedge_fallback(
    const float* __restrict__ features, const float* __restrict__ W1,
    const float* __restrict__ b1, const float* __restrict__ W2,
    const float* __restrict__ b2, const float* __restrict__ W3,
    const float* __restrict__ b3, float* __restrict__ out) {
    const int b = blockIdx.x;
    const int tid = threadIdx.x;
    const int j = tid & 63;
    const int s = tid >> 6;

    __shared__ __align__(16) float sF[NT * IND];
    __shared__ __align__(16) float sSig[128];
    __shared__ float sA[IND], sB[IND], sC[IND * IND];
    __shared__ float sRel[IND];
    __shared__ __align__(16) float sPart[4 * 64];
    __shared__ __align__(16) float sH1[64];

    for (int idx = tid; idx < NT * IND; idx += 256)
        sF[idx] = features[b * (NT * IND) + idx];
    if (tid < 100) sC[tid] = 0.f;
    else if (tid < 110) sA[tid - 100] = 0.f;
    else if (tid < 120) sB[tid - 110] = 0.f;
    else if (tid >= 121 && tid < 128) sSig[tid] = 0.f;

    float vs[32], vb[32], vc[32];
#pragma unroll
    for (int mm = 0; mm < 32; ++mm) {
        int mp = 32 * s + mm;
        if (mp < 121) {
            vs[mm] = W1[(11 + mp) * 64 + j] + W1[(132 + mp) * 64 + j];
            vb[mm] = W1[(253 + mp) * 64 + j];
            vc[mm] = W1[(374 + mp) * 64 + j];
        } else { vs[mm] = 0.f; vb[mm] = 0.f; vc[mm] = 0.f; }
    }
    float ex[17];
#pragma unroll
    for (int q = 0; q < 17; ++q) ex[q] = 0.f;
    if (s == 1) {
#pragma unroll
        for (int q = 0; q < 11; ++q) ex[q] = W1[q * 64 + j];
    } else if (s == 2) {
#pragma unroll
        for (int q = 0; q < 10; ++q) ex[q] = W1[(512 + q) * 64 + j];
        ex[10] = b1[j];
    } else if (s == 3) {
#pragma unroll
        for (int q = 0; q < 17; ++q) ex[q] = W1[(495 + q) * 64 + j];
    }
    float w2p[16];
#pragma unroll
    for (int ii = 0; ii < 16; ++ii) w2p[ii] = W2[(16 * s + ii) * 64 + j];

    float w1l = 0.f, b2j = 0.f, w3j = 0.f, b3v = 0.f;
    if (s == 0) { w1l = W1[522 * 64 + j]; b2j = b2[j]; w3j = W3[j]; b3v = b3[0]; }
    float delta = 0.f;

    __syncthreads();

    for (int m = 0; m < NT; ++m) {
        if (m > 0) {
            if (tid < 100) {
                int i = tid / 10, c = tid % 10;
                float rp = sF[(m - 1) * 10 + i] - sF[i];
                float ic = sF[m * 10 + c] - sF[(m - 1) * 10 + c];
                sC[tid] += rp * ic;
            } else if (tid < 110) {
                int i = tid - 100;
                sA[i] += (float)(m - 1) * (sF[m * 10 + i] - sF[(m - 1) * 10 + i]);
            } else if (tid < 120) {
                int i = tid - 110;
                sB[i] += sF[(m - 1) * 10 + i] - sF[i];
            }
            __syncthreads();
            float inv_k = 1.0f / (float)m;
            if (tid == 0) sSig[0] = 0.5f * (float)(m - 1) * inv_k;
            else if (tid < 11) sSig[tid] = inv_k * sA[tid - 1];
            else if (tid < 121) {
                int i = tid / 11 - 1, c = tid % 11;
                sSig[tid] = (c == 0) ? inv_k * sB[i] : sC[i * 10 + (c - 1)];
            } else if (tid < 131) {
                int f = tid - 121;
                sRel[f] = sF[m * 10 + f] - sF[f];
            }
            __syncthreads();
        }
        float part = 0.f;
        if (m > 0) {
            float pa = 0.f, pb = 0.f, pc = 0.f;
#pragma unroll
            for (int q = 0; q < 8; ++q) {
                float4 sv = *(const float4*)&sSig[32 * s + 4 * q];
                pa = fmaf(sv.x, vs[4 * q + 0], pa);
                pb = fmaf(sv.x, vb[4 * q + 0], pb);
                pc = fmaf(sv.x, vc[4 * q + 0], pc);
                pa = fmaf(sv.y, vs[4 * q + 1], pa);
                pb = fmaf(sv.y, vb[4 * q + 1], pb);
                pc = fmaf(sv.y, vc[4 * q + 1], pc);
                pa = fmaf(sv.z, vs[4 * q + 2], pa);
                pb = fmaf(sv.z, vb[4 * q + 2], pb);
                pc = fmaf(sv.z, vc[4 * q + 2], pc);
                pa = fmaf(sv.w, vs[4 * q + 3], pa);
                pb = fmaf(sv.w, vb[4 * q + 3], pb);
                pc = fmaf(sv.w, vc[4 * q + 3], pc);
            }
            part = pa + sRel[0] * pb + sRel[1] * pc;
            if (s == 3) {
                float pd = 0.f;
#pragma unroll
                for (int q = 0; q < 17; ++q) pd = fmaf(sSig[q], ex[q], pd);
                part = fmaf(sRel[2], pd, part);
            }
            if (s == 1) {
                part += ex[0];
#pragma unroll
                for (int i = 0; i < 10; ++i) part = fmaf(sRel[i], ex[1 + i], part);
            }
        }
        if (s == 2) {
            float pf = ex[10];
#pragma unroll
            for (int f = 0; f < 10; ++f) pf = fmaf(sF[m * 10 + f], ex[f], pf);
            part += pf;
        }
        sPart[s * 64 + j] = part;
        __syncthreads();
        if (s == 0) {
            float x = sPart[j] + sPart[64 + j] + sPart[128 + j] + sPart[192 + j];
            sH1[j] = fmaxf(fmaf(delta, w1l, x), 0.f);
        }
        __syncthreads();
        {
            float hp = 0.f;
#pragma unroll
            for (int q = 0; q < 4; ++q) {
                float4 hv = *(const float4*)&sH1[16 * s + 4 * q];
                hp = fmaf(hv.x, w2p[4 * q + 0], hp);
                hp = fmaf(hv.y, w2p[4 * q + 1], hp);
                hp = fmaf(hv.z, w2p[4 * q + 2], hp);
                hp = fmaf(hv.w, w2p[4 * q + 3], hp);
            }
            sPart[s * 64 + j] = hp;
        }
        __syncthreads();
        if (s == 0) {
            float x2 = sPart[j] + sPart[64 + j] + sPart[128 + j] + sPart[192 + j] + b2j;
            float h2 = fmaxf(x2, 0.f);
            float dv = h2 * w3j;
#pragma unroll
            for (int off = 32; off > 0; off >>= 1) dv += __shfl_xor(dv, off, 64);
            delta = dv + b3v;
            if (j == 0) out[b * NT + m] = delta;
        }
        __syncthreads();
    }
}

extern "C" void kernel_launch(void* const* d_in, const int* in_sizes, int n_in,
                              void* d_out, int out_size, void* d_ws, size_t ws_size,
                              hipStream_t stream) {
    const float* features = (const float*)d_in[0];
    const float* W1 = (const float*)d_in[1];
    const float* b1 = (const float*)d_in[2];
    const float* W2 = (const float*)d_in[3];
    const float* b2 = (const float*)d_in[4];
    const float* W3 = (const float*)d_in[5];
    const float* b3 = (const float*)d_in[6];
    float* out = (float*)d_out;

    const size_t wmf_bytes = (size_t)WMF_HALVES * 2;                 // 57344
    const size_t w_pad     = ((wmf_bytes + 255) / 256) * 256;
    const size_t pre_bytes = (size_t)NB * NT * HID * sizeof(float);  // 64 MiB
    if (ws_size >= w_pad + pre_bytes) {
        unsigned short* Wmf = (unsigned short*)d_ws;
        float* pre1 = (float*)((char*)d_ws + w_pad);
        pack_mfma_kernel<<<(WMF_HALVES + 255) / 256, 256, 0, stream>>>(W1, b1, Wmf);
        presig9_kernel<<<NB, 256, 0, stream>>>(features, Wmf, pre1);
        scan2_kernel<<<NB / 2, 64, 0, stream>>>(pre1, W1, W2, b2, W3, b3, out);
    } else {
        logsig_hedge_fallback<<<NB, 256, 0, stream>>>(features, W1, b1, W2, b2, W3, b3, out);
    }
}

// Round 2
// 326.645 us; speedup vs baseline: 1.0951x; 1.0951x over previous
//
#include <hip/hip_runtime.h>

#define NB 1024
#define NT 256
#define IND 10
#define HID 64

#define KSTEPS 14              // K = 448 (14 x 32)
#define XS 456                 // X row stride in halves (456/8=57 odd -> conflict-free b128)
#define WMF_HALVES (KSTEPS * 4 * 64 * 8)   // 28672 halves = 57344 B

typedef short bf16x8 __attribute__((ext_vector_type(8)));
typedef float f32x4 __attribute__((ext_vector_type(4)));

__device__ __forceinline__ int qmap(int kk) {
    if (kk < 10) return 1 + kk;
    if (kk < 20) return 11 * (kk - 10 + 1);
    int i = (kk - 20) / 10, c = (kk - 20) % 10;
    return 11 * (i + 1) + 1 + c;
}

__device__ __forceinline__ unsigned bf16rne(float x) {
    unsigned u = __float_as_uint(x);
    return (u + 0x7fffu + ((u >> 16) & 1u)) >> 16;
}
__device__ __forceinline__ unsigned pk2(float a, float b) {
    return bf16rne(a) | (bf16rne(b) << 16);
}

// X column semantics (K=448):
//  [0,128):   P (wave slice w at 32w+i, i<30; scaled by inv_k for comps<20)
//  [128,256): rel0 * P
//  [256,384): rel1 * P
//  [384,400): rel2 * Pd (Pd = P[0..9], P[10], P[20..24])
//  [400,410): rel ; [410,420): F ; [420,424): ttv, ttv*rel0, ttv*rel1, ttv*rel2
//  [424]: gate ; [425]: 1.0 (bias) ; rest 0
__device__ float wm_value(int kk, int j, const float* __restrict__ W1,
                          const float* __restrict__ b1) {
    if (kk < 384) {
        int sec = kk >> 7;
        int rem = kk & 127;
        int w = rem >> 5, i = rem & 31;
        if (i >= 30) return 0.f;
        int q = qmap(30 * w + i);
        if (sec == 0) return W1[(11 + q) * 64 + j] + W1[(132 + q) * 64 + j];
        if (sec == 1) return W1[(253 + q) * 64 + j];
        return W1[(374 + q) * 64 + j];
    }
    if (kk < 400) {
        int i = kk - 384;
        if (i < 10) return W1[(496 + i) * 64 + j];
        if (i == 10) return W1[506 * 64 + j];
        return W1[(507 + (i - 11)) * 64 + j];
    }
    if (kk < 410) return W1[(1 + (kk - 400)) * 64 + j];
    if (kk < 420) return W1[(512 + (kk - 410)) * 64 + j];
    if (kk == 420) return W1[11 * 64 + j] + W1[132 * 64 + j];
    if (kk == 421) return W1[253 * 64 + j];
    if (kk == 422) return W1[374 * 64 + j];
    if (kk == 423) return W1[495 * 64 + j];
    if (kk == 424) return W1[0 * 64 + j];
    if (kk == 425) return b1[j];
    return 0.f;
}

// Wmf in exact B-fragment order: record (s, jb) is 64 lanes x 8 halves:
// lane (n = lane&15, quad = lane>>4) holds Wm[32s + quad*8 + idx][16jb + n].
__global__ void pack_mfma_kernel(const float* __restrict__ W1,
                                 const float* __restrict__ b1,
                                 unsigned short* __restrict__ Wmf) {
    int idx = blockIdx.x * 256 + threadIdx.x;
    if (idx >= WMF_HALVES) return;
    int half = idx & 7;
    int lane = (idx >> 3) & 63;
    int rec = idx >> 9;           // s*4 + jb
    int s = rec >> 2, jb = rec & 3;
    int kk = 32 * s + (lane >> 4) * 8 + half;
    int j = 16 * jb + (lane & 15);
    Wmf[idx] = (unsigned short)bf16rne(wm_value(kk, j, W1, b1));
}

// ---------------------------------------------------------------------------
// presig v9 (unchanged): scan phase spill-free; j-phase MFMA GEMM
// pre[64t][64j] = X[64t][448] . Wm[448][64j] in bf16.
// ---------------------------------------------------------------------------
__global__ __launch_bounds__(256, 1) void presig9_kernel(
    const float* __restrict__ features, const unsigned short* __restrict__ Wmf,
    float* __restrict__ pre1) {
    const int b = blockIdx.x;
    const int tid = threadIdx.x;
    const int l = tid & 63;
    const int wu = tid >> 6;

    __shared__ __align__(16) float sF[NT * IND];            // 10240 B
    __shared__ __align__(16) unsigned short sX[64 * XS];    // 58368 B
    __shared__ float sBase[128];                            // 512 B

    {
        const float4* src = (const float4*)(features + b * (NT * IND));
        float4* dst = (float4*)sF;
        for (int e = tid; e < NT * IND / 4; e += 256) dst[e] = src[e];
    }
    float f0[IND];
#pragma unroll
    for (int c = 0; c < IND; ++c) f0[c] = features[b * (NT * IND) + c];

    if (tid < 128) sBase[tid] = 0.f;
    __syncthreads();   // B0: sF + sBase ready

    for (int tile = 0; tile < 4; ++tile) {
        const int t0 = tile * 64;

        // ---- scan phase (identical math to presig7, proven) ----
        const int r = t0 + l;
        float rf = (float)r;
        float fr[IND], rel[IND], inc[IND];
#pragma unroll
        for (int c = 0; c < IND; ++c) fr[c] = sF[r * IND + c];
#pragma unroll
        for (int c = 0; c < IND; ++c) rel[c] = fr[c] - f0[c];
        {
            bool last = (r >= NT - 1);
#pragma unroll
            for (int c = 0; c < IND; ++c)
                inc[c] = last ? 0.f : (sF[(r + 1) * IND + c] - fr[c]);
        }
        float p[30], own[30];
        if (wu == 0) {
#pragma unroll
            for (int c = 0; c < 10; ++c) p[c] = rf * inc[c];
#pragma unroll
            for (int i = 0; i < 10; ++i) p[10 + i] = rel[i];
#pragma unroll
            for (int c = 0; c < 10; ++c) p[20 + c] = rel[0] * inc[c];
        } else {
            const int i0 = 3 * wu - 2;
#pragma unroll
            for (int q = 0; q < 30; ++q) {
                int i = i0 + q / 10, c = q % 10;
                p[q] = rel[i] * inc[c];
            }
        }
#pragma unroll
        for (int i = 0; i < 30; ++i) own[i] = p[i];
#pragma unroll
        for (int dsh = 0; dsh < 6; ++dsh) {
            const int d = 1 << dsh;
            bool ok = (l >= d);
#pragma unroll
            for (int i = 0; i < 30; ++i) {
                float v = __shfl_up(p[i], d, 64);
                if (ok) p[i] += v;
            }
        }
        float inv_r = (r > 0) ? 1.f / rf : 0.f;
        float v[30];
#pragma unroll
        for (int i = 0; i < 30; ++i) {
            float x = sBase[wu * 32 + i] + p[i] - own[i];
            if (wu == 0 && i < 20) x *= inv_r;
            v[i] = x;
        }

        // ---- build X (bf16), immediate uint4 stores (no big live arrays) ----
        {
            float g0 = rel[0], g1 = rel[1];
            uint4* xr = (uint4*)&sX[l * XS];           // raw P at halves 32*wu
            uint4* x0 = (uint4*)&sX[l * XS + 128];     // rel0*P
            uint4* x1 = (uint4*)&sX[l * XS + 256];     // rel1*P
#pragma unroll
            for (int q = 0; q < 3; ++q) {
                uint4 tr, t0v, t1v;
                tr.x = pk2(v[8*q+0], v[8*q+1]); tr.y = pk2(v[8*q+2], v[8*q+3]);
                tr.z = pk2(v[8*q+4], v[8*q+5]); tr.w = pk2(v[8*q+6], v[8*q+7]);
                t0v.x = pk2(g0*v[8*q+0], g0*v[8*q+1]); t0v.y = pk2(g0*v[8*q+2], g0*v[8*q+3]);
                t0v.z = pk2(g0*v[8*q+4], g0*v[8*q+5]); t0v.w = pk2(g0*v[8*q+6], g0*v[8*q+7]);
                t1v.x = pk2(g1*v[8*q+0], g1*v[8*q+1]); t1v.y = pk2(g1*v[8*q+2], g1*v[8*q+3]);
                t1v.z = pk2(g1*v[8*q+4], g1*v[8*q+5]); t1v.w = pk2(g1*v[8*q+6], g1*v[8*q+7]);
                xr[wu * 4 + q] = tr; x0[wu * 4 + q] = t0v; x1[wu * 4 + q] = t1v;
            }
            {   // tail: v[24..29] + 2 zero halves
                uint4 tr, t0v, t1v;
                tr.x = pk2(v[24], v[25]); tr.y = pk2(v[26], v[27]);
                tr.z = pk2(v[28], v[29]); tr.w = 0u;
                t0v.x = pk2(g0*v[24], g0*v[25]); t0v.y = pk2(g0*v[26], g0*v[27]);
                t0v.z = pk2(g0*v[28], g0*v[29]); t0v.w = 0u;
                t1v.x = pk2(g1*v[24], g1*v[25]); t1v.y = pk2(g1*v[26], g1*v[27]);
                t1v.z = pk2(g1*v[28], g1*v[29]); t1v.w = 0u;
                xr[wu * 4 + 3] = tr; x0[wu * 4 + 3] = t0v; x1[wu * 4 + 3] = t1v;
            }
        }
        if (wu == 0) {   // extras: halves [384,456) of row l
            float g2 = rel[2];
            float ttv = 0.5f * (rf - 1.f) * inv_r;
            float gate = (r > 0) ? 1.f : 0.f;
            uint4* xe = (uint4*)&sX[l * XS + 384];
            uint4 u;
            u.x = pk2(g2*v[0], g2*v[1]);  u.y = pk2(g2*v[2], g2*v[3]);
            u.z = pk2(g2*v[4], g2*v[5]);  u.w = pk2(g2*v[6], g2*v[7]);
            xe[0] = u;
            u.x = pk2(g2*v[8], g2*v[9]);  u.y = pk2(g2*v[10], g2*v[20]);
            u.z = pk2(g2*v[21], g2*v[22]); u.w = pk2(g2*v[23], g2*v[24]);
            xe[1] = u;
            u.x = pk2(rel[0], rel[1]); u.y = pk2(rel[2], rel[3]);
            u.z = pk2(rel[4], rel[5]); u.w = pk2(rel[6], rel[7]);
            xe[2] = u;
            u.x = pk2(rel[8], rel[9]); u.y = pk2(fr[0], fr[1]);
            u.z = pk2(fr[2], fr[3]);   u.w = pk2(fr[4], fr[5]);
            xe[3] = u;
            u.x = pk2(fr[6], fr[7]); u.y = pk2(fr[8], fr[9]);
            u.z = pk2(ttv, ttv * rel[0]); u.w = pk2(ttv * rel[1], ttv * rel[2]);
            xe[4] = u;
            u.x = pk2(gate, 1.0f); u.y = 0u; u.z = 0u; u.w = 0u;
            xe[5] = u;
            u.x = 0u; u.y = 0u; u.z = 0u; u.w = 0u;
            xe[6] = u; xe[7] = u;
        }
        if (l == 63) {
#pragma unroll
            for (int i = 0; i < 30; ++i) sBase[wu * 32 + i] += p[i];
        }
        __syncthreads();   // Bx: X complete (cross-wave reads next)

        // ---- MFMA j-phase: wave wu computes t-rows [16wu,16wu+16) x all j ----
        {
            const int m = l & 15, quad = l >> 4;
            const unsigned short* arow = &sX[(16 * wu + m) * XS + 8 * quad];
            const bf16x8* bp = (const bf16x8*)Wmf;
            f32x4 ac0 = {0.f, 0.f, 0.f, 0.f}, ac1 = ac0, ac2 = ac0, ac3 = ac0;
#pragma unroll
            for (int s = 0; s < KSTEPS; ++s) {
                bf16x8 af = *(const bf16x8*)(arow + 32 * s);
                bf16x8 bf0 = bp[(s * 4 + 0) * 64 + l];
                bf16x8 bf1 = bp[(s * 4 + 1) * 64 + l];
                bf16x8 bf2 = bp[(s * 4 + 2) * 64 + l];
                bf16x8 bf3 = bp[(s * 4 + 3) * 64 + l];
                ac0 = __builtin_amdgcn_mfma_f32_16x16x32_bf16(af, bf0, ac0, 0, 0, 0);
                ac1 = __builtin_amdgcn_mfma_f32_16x16x32_bf16(af, bf1, ac1, 0, 0, 0);
                ac2 = __builtin_amdgcn_mfma_f32_16x16x32_bf16(af, bf2, ac2, 0, 0, 0);
                ac3 = __builtin_amdgcn_mfma_f32_16x16x32_bf16(af, bf3, ac3, 0, 0, 0);
            }
            float* op = pre1 + b * (NT * HID) + (t0 + 16 * wu) * HID + m;
            const int rowb = quad * 4;
#pragma unroll
            for (int reg = 0; reg < 4; ++reg) {
                op[(rowb + reg) * HID + 0]  = ac0[reg];
                op[(rowb + reg) * HID + 16] = ac1[reg];
                op[(rowb + reg) * HID + 32] = ac2[reg];
                op[(rowb + reg) * HID + 48] = ac3[reg];
            }
        }
        __syncthreads();   // Be: all X reads done before next tile rewrites
    }
}

// ---------------------------------------------------------------------------
// scan v3 (scan4_kernel): 4 cooperating waves per block, 1024 blocks.
// Post-mortem of v2: single-wave ILP-doubling failed (VGPR spill of pinned
// W2 + halved SIMD coverage).  Fix: shrink the per-wave W2 working set 4x
// (16 floats/lane -- registers hold it without a fight), keep 1024 blocks
// (16 waves/CU -> real TLP).  Wave w owns W2 rows [16w,16w+16): partial
// GEMV with v_readlane h1 broadcasts (SGPR-operand fmaf).  Full h1 and the
// final DPP reduce are computed redundantly per wave (bit-identical) so the
// step needs ONE barrier + ping-pong partial buffer.  Raw
// s_waitcnt lgkmcnt(0); s_barrier (memory clobber) -- NOT __syncthreads --
// so the 8-deep vmcnt prefetch ring survives the per-step barrier.
// ---------------------------------------------------------------------------
template <int CTRL, int RMASK>
__device__ __forceinline__ float dpp_add(float x) {
    int v = __builtin_amdgcn_update_dpp(0, __float_as_int(x), CTRL, RMASK, 0xf, false);
    return x + __int_as_float(v);
}

__global__ __launch_bounds__(256, 1) void scan4_kernel(
    const float* __restrict__ pre1, const float* __restrict__ W1,
    const float* __restrict__ W2, const float* __restrict__ b2,
    const float* __restrict__ W3, const float* __restrict__ b3,
    float* __restrict__ out) {
    const int b = blockIdx.x;
    const int j = threadIdx.x & 63;
    const int w = __builtin_amdgcn_readfirstlane(threadIdx.x >> 6);

    __shared__ __align__(16) float sPart[2][4 * 64];   // ping-pong partials

    float w2r[16];
#pragma unroll
    for (int ii = 0; ii < 16; ++ii) w2r[ii] = W2[(16 * w + ii) * 64 + j];
    float w1l = W1[522 * 64 + j];
    float b2j = b2[j], w3j = W3[j], b3v = b3[0];

    const float* pb_ = pre1 + b * (NT * HID);
    float delta = 0.f;
    float outbuf = 0.f;

#define SCAN_STEP4(pv, mm) { \
        float h1 = fmaxf(fmaf(delta, w1l, (pv)), 0.f); \
        float hb[16]; \
        _Pragma("unroll") \
        for (int ii = 0; ii < 16; ++ii) \
            hb[ii] = __uint_as_float(__builtin_amdgcn_readlane( \
                __float_as_uint(h1), 16 * w + ii)); \
        float a0 = 0.f, a1 = 0.f, a2 = 0.f, a3 = 0.f; \
        _Pragma("unroll") \
        for (int q = 0; q < 4; ++q) { \
            a0 = fmaf(w2r[4 * q + 0], hb[4 * q + 0], a0); \
            a1 = fmaf(w2r[4 * q + 1], hb[4 * q + 1], a1); \
            a2 = fmaf(w2r[4 * q + 2], hb[4 * q + 2], a2); \
            a3 = fmaf(w2r[4 * q + 3], hb[4 * q + 3], a3); \
        } \
        sPart[(mm) & 1][w * 64 + j] = (a0 + a1) + (a2 + a3); \
        asm volatile("s_waitcnt lgkmcnt(0)\n\ts_barrier" ::: "memory"); \
        float p0 = sPart[(mm) & 1][j]; \
        float p1 = sPart[(mm) & 1][64 + j]; \
        float p2 = sPart[(mm) & 1][128 + j]; \
        float p3 = sPart[(mm) & 1][192 + j]; \
        float h2 = fmaxf((p0 + p1) + (p2 + p3) + b2j, 0.f); \
        float qv = h2 * w3j; \
        qv = dpp_add<0x111, 0xf>(qv); \
        qv = dpp_add<0x112, 0xf>(qv); \
        qv = dpp_add<0x114, 0xf>(qv); \
        qv = dpp_add<0x118, 0xf>(qv); \
        qv = dpp_add<0x142, 0xa>(qv); \
        qv = dpp_add<0x143, 0xc>(qv); \
        float tot = __uint_as_float(__builtin_amdgcn_readlane(__float_as_uint(qv), 63)); \
        delta = tot + b3v; \
        if (w == 0) { \
            if (j == ((mm) & 63)) outbuf = delta; \
            if (((mm) & 63) == 63) out[b * NT + ((mm) & ~63) + j] = outbuf; \
        } }

    float r0 = pb_[0 * 64 + j], r1 = pb_[1 * 64 + j], r2 = pb_[2 * 64 + j],
          r3 = pb_[3 * 64 + j], r4 = pb_[4 * 64 + j], r5 = pb_[5 * 64 + j],
          r6 = pb_[6 * 64 + j], r7 = pb_[7 * 64 + j];
    for (int g = 0; g < NT; g += 8) {
        int nb = g + 8;
        float n0 = pb_[min(nb + 0, NT - 1) * 64 + j];
        float n1 = pb_[min(nb + 1, NT - 1) * 64 + j];
        float n2 = pb_[min(nb + 2, NT - 1) * 64 + j];
        float n3 = pb_[min(nb + 3, NT - 1) * 64 + j];
        float n4 = pb_[min(nb + 4, NT - 1) * 64 + j];
        float n5 = pb_[min(nb + 5, NT - 1) * 64 + j];
        float n6 = pb_[min(nb + 6, NT - 1) * 64 + j];
        float n7 = pb_[min(nb + 7, NT - 1) * 64 + j];
        SCAN_STEP4(r0, g + 0)
        SCAN_STEP4(r1, g + 1)
        SCAN_STEP4(r2, g + 2)
        SCAN_STEP4(r3, g + 3)
        SCAN_STEP4(r4, g + 4)
        SCAN_STEP4(r5, g + 5)
        SCAN_STEP4(r6, g + 6)
        SCAN_STEP4(r7, g + 7)
        r0 = n0; r1 = n1; r2 = n2; r3 = n3; r4 = n4; r5 = n5; r6 = n6; r7 = n7;
    }
#undef SCAN_STEP4
}

// ---------------------------------------------------------------------------
// Fallback (round-1 fused kernel) if workspace is too small.
// ---------------------------------------------------------------------------
__global__ __launch_bounds__(256) void logsig_hedge_fallback(
    const float* __restrict__ features, const float* __restrict__ W1,
    const float* __restrict__ b1, const float* __restrict__ W2,
    const float* __restrict__ b2, const float* __restrict__ W3,
    const float* __restrict__ b3, float* __restrict__ out) {
    const int b = blockIdx.x;
    const int tid = threadIdx.x;
    const int j = tid & 63;
    const int s = tid >> 6;

    __shared__ __align__(16) float sF[NT * IND];
    __shared__ __align__(16) float sSig[128];
    __shared__ float sA[IND], sB[IND], sC[IND * IND];
    __shared__ float sRel[IND];
    __shared__ __align__(16) float sPart[4 * 64];
    __shared__ __align__(16) float sH1[64];

    for (int idx = tid; idx < NT * IND; idx += 256)
        sF[idx] = features[b * (NT * IND) + idx];
    if (tid < 100) sC[tid] = 0.f;
    else if (tid < 110) sA[tid - 100] = 0.f;
    else if (tid < 120) sB[tid - 110] = 0.f;
    else if (tid >= 121 && tid < 128) sSig[tid] = 0.f;

    float vs[32], vb[32], vc[32];
#pragma unroll
    for (int mm = 0; mm < 32; ++mm) {
        int mp = 32 * s + mm;
        if (mp < 121) {
            vs[mm] = W1[(11 + mp) * 64 + j] + W1[(132 + mp) * 64 + j];
            vb[mm] = W1[(253 + mp) * 64 + j];
            vc[mm] = W1[(374 + mp) * 64 + j];
        } else { vs[mm] = 0.f; vb[mm] = 0.f; vc[mm] = 0.f; }
    }
    float ex[17];
#pragma unroll
    for (int q = 0; q < 17; ++q) ex[q] = 0.f;
    if (s == 1) {
#pragma unroll
        for (int q = 0; q < 11; ++q) ex[q] = W1[q * 64 + j];
    } else if (s == 2) {
#pragma unroll
        for (int q = 0; q < 10; ++q) ex[q] = W1[(512 + q) * 64 + j];
        ex[10] = b1[j];
    } else if (s == 3) {
#pragma unroll
        for (int q = 0; q < 17; ++q) ex[q] = W1[(495 + q) * 64 + j];
    }
    float w2p[16];
#pragma unroll
    for (int ii = 0; ii < 16; ++ii) w2p[ii] = W2[(16 * s + ii) * 64 + j];

    float w1l = 0.f, b2j = 0.f, w3j = 0.f, b3v = 0.f;
    if (s == 0) { w1l = W1[522 * 64 + j]; b2j = b2[j]; w3j = W3[j]; b3v = b3[0]; }
    float delta = 0.f;

    __syncthreads();

    for (int m = 0; m < NT; ++m) {
        if (m > 0) {
            if (tid < 100) {
                int i = tid / 10, c = tid % 10;
                float rp = sF[(m - 1) * 10 + i] - sF[i];
                float ic = sF[m * 10 + c] - sF[(m - 1) * 10 + c];
                sC[tid] += rp * ic;
            } else if (tid < 110) {
                int i = tid - 100;
                sA[i] += (float)(m - 1) * (sF[m * 10 + i] - sF[(m - 1) * 10 + i]);
            } else if (tid < 120) {
                int i = tid - 110;
                sB[i] += sF[(m - 1) * 10 + i] - sF[i];
            }
            __syncthreads();
            float inv_k = 1.0f / (float)m;
            if (tid == 0) sSig[0] = 0.5f * (float)(m - 1) * inv_k;
            else if (tid < 11) sSig[tid] = inv_k * sA[tid - 1];
            else if (tid < 121) {
                int i = tid / 11 - 1, c = tid % 11;
                sSig[tid] = (c == 0) ? inv_k * sB[i] : sC[i * 10 + (c - 1)];
            } else if (tid < 131) {
                int f = tid - 121;
                sRel[f] = sF[m * 10 + f] - sF[f];
            }
            __syncthreads();
        }
        float part = 0.f;
        if (m > 0) {
            float pa = 0.f, pb = 0.f, pc = 0.f;
#pragma unroll
            for (int q = 0; q < 8; ++q) {
                float4 sv = *(const float4*)&sSig[32 * s + 4 * q];
                pa = fmaf(sv.x, vs[4 * q + 0], pa);
                pb = fmaf(sv.x, vb[4 * q + 0], pb);
                pc = fmaf(sv.x, vc[4 * q + 0], pc);
                pa = fmaf(sv.y, vs[4 * q + 1], pa);
                pb = fmaf(sv.y, vb[4 * q + 1], pb);
                pc = fmaf(sv.y, vc[4 * q + 1], pc);
                pa = fmaf(sv.z, vs[4 * q + 2], pa);
                pb = fmaf(sv.z, vb[4 * q + 2], pb);
                pc = fmaf(sv.z, vc[4 * q + 2], pc);
                pa = fmaf(sv.w, vs[4 * q + 3], pa);
                pb = fmaf(sv.w, vb[4 * q + 3], pb);
                pc = fmaf(sv.w, vc[4 * q + 3], pc);
            }
            part = pa + sRel[0] * pb + sRel[1] * pc;
            if (s == 3) {
                float pd = 0.f;
#pragma unroll
                for (int q = 0; q < 17; ++q) pd = fmaf(sSig[q], ex[q], pd);
                part = fmaf(sRel[2], pd, part);
            }
            if (s == 1) {
                part += ex[0];
#pragma unroll
                for (int i = 0; i < 10; ++i) part = fmaf(sRel[i], ex[1 + i], part);
            }
        }
        if (s == 2) {
            float pf = ex[10];
#pragma unroll
            for (int f = 0; f < 10; ++f) pf = fmaf(sF[m * 10 + f], ex[f], pf);
            part += pf;
        }
        sPart[s * 64 + j] = part;
        __syncthreads();
        if (s == 0) {
            float x = sPart[j] + sPart[64 + j] + sPart[128 + j] + sPart[192 + j];
            sH1[j] = fmaxf(fmaf(delta, w1l, x), 0.f);
        }
        __syncthreads();
        {
            float hp = 0.f;
#pragma unroll
            for (int q = 0; q < 4; ++q) {
                float4 hv = *(const float4*)&sH1[16 * s + 4 * q];
                hp = fmaf(hv.x, w2p[4 * q + 0], hp);
                hp = fmaf(hv.y, w2p[4 * q + 1], hp);
                hp = fmaf(hv.z, w2p[4 * q + 2], hp);
                hp = fmaf(hv.w, w2p[4 * q + 3], hp);
            }
            sPart[s * 64 + j] = hp;
        }
        __syncthreads();
        if (s == 0) {
            float x2 = sPart[j] + sPart[64 + j] + sPart[128 + j] + sPart[192 + j] + b2j;
            float h2 = fmaxf(x2, 0.f);
            float dv = h2 * w3j;
#pragma unroll
            for (int off = 32; off > 0; off >>= 1) dv += __shfl_xor(dv, off, 64);
            delta = dv + b3v;
            if (j == 0) out[b * NT + m] = delta;
        }
        __syncthreads();
    }
}

extern "C" void kernel_launch(void* const* d_in, const int* in_sizes, int n_in,
                              void* d_out, int out_size, void* d_ws, size_t ws_size,
                              hipStream_t stream) {
    const float* features = (const float*)d_in[0];
    const float* W1 = (const float*)d_in[1];
    const float* b1 = (const float*)d_in[2];
    const float* W2 = (const float*)d_in[3];
    const float* b2 = (const float*)d_in[4];
    const float* W3 = (const float*)d_in[5];
    const float* b3 = (const float*)d_in[6];
    float* out = (float*)d_out;

    const size_t wmf_bytes = (size_t)WMF_HALVES * 2;                 // 57344
    const size_t w_pad     = ((wmf_bytes + 255) / 256) * 256;
    const size_t pre_bytes = (size_t)NB * NT * HID * sizeof(float);  // 64 MiB
    if (ws_size >= w_pad + pre_bytes) {
        unsigned short* Wmf = (unsigned short*)d_ws;
        float* pre1 = (float*)((char*)d_ws + w_pad);
        pack_mfma_kernel<<<(WMF_HALVES + 255) / 256, 256, 0, stream>>>(W1, b1, Wmf);
        presig9_kernel<<<NB, 256, 0, stream>>>(features, Wmf, pre1);
        scan4_kernel<<<NB, 256, 0, stream>>>(pre1, W1, W2, b2, W3, b3, out);
    } else {
        logsig_hedge_fallback<<<NB, 256, 0, stream>>>(features, W1, b1, W2, b2, W3, b3, out);
    }
}